// Round 2
// baseline (739.980 us; speedup 1.0000x reference)
//
#include <hip/hip_runtime.h>
#include <math.h>

#define B_  32
#define T_  4096
#define H_  256
#define D_  512

// ws layout (bytes):
//   pre    : float [32*256]    @ 0        (h_proj + b_attn)
//   we_hi  : ushort[256*512]   @ 32768
//   scores : float [32*4096]   @ 557056   (we_lo slot retired, offset kept)
#define WS_PRE    0
#define WS_WEHI   32768
#define WS_SCORES 557056

using short8  = __attribute__((ext_vector_type(8))) short;
using float4v = __attribute__((ext_vector_type(4))) float;

__device__ __forceinline__ unsigned short f32_to_bf16_rne(float x) {
    unsigned u = __float_as_uint(x);
    unsigned r = u + 0x7fffu + ((u >> 16) & 1u);
    return (unsigned short)(r >> 16);
}
__device__ __forceinline__ float bf16_to_f32(unsigned short h) {
    return __uint_as_float(((unsigned)h) << 16);
}

// ---------------------------------------------------------------- prep ------
// blocks 0..31 : pre[b][h] = b_attn[h] + hidden[b] . W_attn[h, 0:512]
// blocks 32..39: W_e = W_attn[:, 512:1024] -> bf16 hi into ws (rne)
// block  40    : zero the context region of d_out
__global__ __launch_bounds__(256)
void prep_kernel(const float* __restrict__ hidden,
                 const float* __restrict__ W_attn,
                 const float* __restrict__ b_attn,
                 unsigned char* __restrict__ ws,
                 float* __restrict__ out_ctx) {
    int blk = blockIdx.x;
    int tid = threadIdx.x;
    if (blk < 32) {
        int b = blk, h = tid;
        const float4* hv = (const float4*)(hidden + b * D_);
        const float4* wv = (const float4*)(W_attn + (size_t)h * 1024);
        float s = 0.f;
        #pragma unroll 4
        for (int d4 = 0; d4 < D_ / 4; ++d4) {
            float4 a = hv[d4], w = wv[d4];
            s += a.x * w.x + a.y * w.y + a.z * w.z + a.w * w.w;
        }
        ((float*)(ws + WS_PRE))[b * H_ + h] = s + b_attn[h];
    } else if (blk < 40) {
        int base = (blk - 32) * 16384 + tid;
        unsigned short* whi = (unsigned short*)(ws + WS_WEHI);
        #pragma unroll 4
        for (int i = 0; i < 64; ++i) {
            int idx = base + i * 256;          // 0..131071
            int n = idx >> 9, k = idx & 511;
            float x = W_attn[(size_t)n * 1024 + 512 + k];
            whi[idx] = f32_to_bf16_rne(x);
        }
    } else {
        for (int i = tid; i < B_ * D_; i += 256) out_ctx[i] = 0.f;
    }
}

// --------------------------------------------------- GEMM + tanh + v-dot ----
// grid = 1024 blocks (M-tiles of 128 rows), 512 threads (8 waves, 2x4 m x n).
// BM=128 x BN=256 (full N) x K=512, BK=32.
// Split-bf16 2-pass: acc += Ah*Bh + Al*Bh   (B rounding err ~2^-9 rel).
#define BM 128
#define BN 256
#define BK 32
#define LDT 40   // LDS row stride in ushorts (80B: keeps b128 16B-aligned)

__global__ __launch_bounds__(512, 6)
void gemm_scores_kernel(const float* __restrict__ enc,
                        const unsigned char* __restrict__ ws_ro,
                        const float* __restrict__ v,
                        float* __restrict__ scores_out) {
    __shared__ unsigned short sAh[BM * LDT], sAl[BM * LDT];
    __shared__ unsigned short sBh[BN * LDT];
    __shared__ float sScore[BM];

    const float*          pre = (const float*)(ws_ro + WS_PRE);
    const unsigned short* weh = (const unsigned short*)(ws_ro + WS_WEHI);

    int tid = threadIdx.x;
    int m0  = blockIdx.x * BM;
    int b   = m0 >> 12;            // 4096 rows per batch, tiles never straddle b

    if (tid < BM) sScore[tid] = 0.f;

    // A staging: lane-contiguous LDS writes. rowA consecutive within a wave.
    int rowA = tid & 127, cgA = tid >> 7;
    const float* gA = enc + (size_t)(m0 + rowA) * D_ + cgA * 8;
    // B staging: thread -> (n-row, 16-ushort half)
    int rowB = tid >> 1, hB = tid & 1;
    const unsigned short* gBh = weh + (size_t)rowB * D_ + hB * 16;

    int wave = tid >> 6, lane = tid & 63;
    int wm = wave & 1, wn = wave >> 1;   // 2 m-waves x 4 n-waves, 64x64 each
    int quad = lane >> 4, l16 = lane & 15;

    float4v acc[4][4] = {};

    // register prefetch buffers
    float a_reg[8];
    uint4 bhr0, bhr1;
    {
        const float4* p = (const float4*)gA;
        *(float4*)(a_reg)     = p[0];
        *(float4*)(a_reg + 4) = p[1];
        bhr0 = ((const uint4*)gBh)[0]; bhr1 = ((const uint4*)gBh)[1];
    }

    const int KIT = D_ / BK;   // 16
    for (int kk = 0; kk < KIT; ++kk) {
        // convert + write staged regs to LDS
        unsigned short hi8[8], lo8[8];
        #pragma unroll
        for (int j = 0; j < 8; ++j) {
            float x = a_reg[j];
            unsigned short h = f32_to_bf16_rne(x);
            hi8[j] = h;
            lo8[j] = f32_to_bf16_rne(x - bf16_to_f32(h));
        }
        *(short8*)&sAh[rowA * LDT + cgA * 8] = *(short8*)hi8;
        *(short8*)&sAl[rowA * LDT + cgA * 8] = *(short8*)lo8;
        *(uint4*)&sBh[rowB * LDT + hB * 16]     = bhr0;
        *(uint4*)&sBh[rowB * LDT + hB * 16 + 8] = bhr1;
        __syncthreads();

        // prefetch next K-chunk (latency hidden behind the MFMA block below)
        if (kk + 1 < KIT) {
            const float4* p = (const float4*)(gA + (kk + 1) * BK);
            *(float4*)(a_reg)     = p[0];
            *(float4*)(a_reg + 4) = p[1];
            const uint4* pbh = (const uint4*)(gBh + (kk + 1) * BK);
            bhr0 = pbh[0]; bhr1 = pbh[1];
        }

        short8 ah[4], al[4], bh[4];
        #pragma unroll
        for (int i = 0; i < 4; ++i) {
            int r = wm * 64 + i * 16 + l16;
            ah[i] = *(const short8*)&sAh[r * LDT + quad * 8];
            al[i] = *(const short8*)&sAl[r * LDT + quad * 8];
        }
        #pragma unroll
        for (int j = 0; j < 4; ++j) {
            int c = wn * 64 + j * 16 + l16;
            bh[j] = *(const short8*)&sBh[c * LDT + quad * 8];
        }
        #pragma unroll
        for (int i = 0; i < 4; ++i) {
            #pragma unroll
            for (int j = 0; j < 4; ++j) {
                acc[i][j] = __builtin_amdgcn_mfma_f32_16x16x32_bf16(ah[i], bh[j], acc[i][j], 0, 0, 0);
                acc[i][j] = __builtin_amdgcn_mfma_f32_16x16x32_bf16(al[i], bh[j], acc[i][j], 0, 0, 0);
            }
        }
        __syncthreads();
    }

    // epilogue: energy = tanh(acc + pre[b][n]); score_row += energy * v[n]
    float rowsum[4][4] = {};
    #pragma unroll
    for (int j = 0; j < 4; ++j) {
        int n = wn * 64 + j * 16 + l16;
        float pv = pre[b * H_ + n];
        float vv = v[n];
        #pragma unroll
        for (int i = 0; i < 4; ++i) {
            #pragma unroll
            for (int r = 0; r < 4; ++r) {
                float e = tanhf(acc[i][j][r] + pv);
                rowsum[i][r] += e * vv;
            }
        }
    }
    // reduce over the 16 lanes sharing a row (low 4 lane bits)
    #pragma unroll
    for (int i = 0; i < 4; ++i) {
        #pragma unroll
        for (int r = 0; r < 4; ++r) {
            float s = rowsum[i][r];
            s += __shfl_xor(s, 1);
            s += __shfl_xor(s, 2);
            s += __shfl_xor(s, 4);
            s += __shfl_xor(s, 8);
            rowsum[i][r] = s;
        }
    }
    if (l16 == 0) {
        #pragma unroll
        for (int i = 0; i < 4; ++i) {
            #pragma unroll
            for (int r = 0; r < 4; ++r) {
                int row = wm * 64 + i * 16 + quad * 4 + r;
                atomicAdd(&sScore[row], rowsum[i][r]);
            }
        }
    }
    __syncthreads();
    if (tid < BM) scores_out[m0 + tid] = sScore[tid];
}

// ------------------------------------------------------------- softmax ------
// one block per batch, 1024 threads, 4 scores each (float4)
__global__ __launch_bounds__(1024)
void softmax_kernel(const float* __restrict__ scores, float* __restrict__ wout) {
    __shared__ float red[16];
    int b = blockIdx.x, tid = threadIdx.x;
    int wave = tid >> 6, lane = tid & 63;
    float4 x = ((const float4*)(scores + (size_t)b * T_))[tid];

    float m = fmaxf(fmaxf(x.x, x.y), fmaxf(x.z, x.w));
    #pragma unroll
    for (int off = 32; off; off >>= 1) m = fmaxf(m, __shfl_xor(m, off));
    if (lane == 0) red[wave] = m;
    __syncthreads();
    if (wave == 0) {
        float t = (lane < 16) ? red[lane] : -1e30f;
        #pragma unroll
        for (int off = 8; off; off >>= 1) t = fmaxf(t, __shfl_xor(t, off));
        if (lane == 0) red[0] = t;
    }
    __syncthreads();
    m = red[0];
    __syncthreads();

    float4 e;
    e.x = expf(x.x - m); e.y = expf(x.y - m);
    e.z = expf(x.z - m); e.w = expf(x.w - m);
    float s = e.x + e.y + e.z + e.w;
    #pragma unroll
    for (int off = 32; off; off >>= 1) s += __shfl_xor(s, off);
    if (lane == 0) red[wave] = s;
    __syncthreads();
    if (wave == 0) {
        float t = (lane < 16) ? red[lane] : 0.f;
        #pragma unroll
        for (int off = 8; off; off >>= 1) t += __shfl_xor(t, off);
        if (lane == 0) red[0] = t;
    }
    __syncthreads();
    float inv = 1.0f / red[0];

    float4 o;
    o.x = e.x * inv; o.y = e.y * inv; o.z = e.z * inv; o.w = e.w * inv;
    ((float4*)(wout + (size_t)b * T_))[tid] = o;
}

// ------------------------------------------------------------- context ------
// grid = 32 b x 64 chunks (64 rows each), 256 threads.
// thread: 4 contiguous d-columns, 2 row-interleaved accumulators
__global__ __launch_bounds__(256)
void context_kernel(const float* __restrict__ enc,
                    const float* __restrict__ w,
                    float* __restrict__ ctx) {
    int blk = blockIdx.x;
    int b = blk >> 6, chunk = blk & 63;
    int tid = threadIdx.x;
    int colg = tid & 127, rh = tid >> 7;
    const float* encb = enc + (size_t)b * T_ * D_;
    int t0 = chunk * 64;

    float4 acc = {0.f, 0.f, 0.f, 0.f};
    #pragma unroll 8
    for (int s = 0; s < 32; ++s) {
        int t = t0 + rh + 2 * s;
        float wt = w[(size_t)b * T_ + t];
        float4 ev = *(const float4*)(encb + (size_t)t * D_ + colg * 4);
        acc.x += wt * ev.x; acc.y += wt * ev.y;
        acc.z += wt * ev.z; acc.w += wt * ev.w;
    }
    __shared__ float4 sred[128];
    if (rh == 1) sred[colg] = acc;
    __syncthreads();
    if (rh == 0) {
        float4 o = sred[colg];
        acc.x += o.x; acc.y += o.y; acc.z += o.z; acc.w += o.w;
        float* dst = ctx + (size_t)b * D_ + colg * 4;
        atomicAdd(dst + 0, acc.x);
        atomicAdd(dst + 1, acc.y);
        atomicAdd(dst + 2, acc.z);
        atomicAdd(dst + 3, acc.w);
    }
}

// ------------------------------------------------------------- launcher -----
extern "C" void kernel_launch(void* const* d_in, const int* in_sizes, int n_in,
                              void* d_out, int out_size, void* d_ws, size_t ws_size,
                              hipStream_t stream) {
    const float* hidden = (const float*)d_in[0];   // (32, 512)
    const float* enc    = (const float*)d_in[1];   // (32, 4096, 512)
    const float* W_attn = (const float*)d_in[2];   // (256, 1024)
    const float* b_attn = (const float*)d_in[3];   // (256,)
    const float* v      = (const float*)d_in[4];   // (256,)
    float* out = (float*)d_out;                    // context(16384) ++ weights(131072)
    unsigned char* ws = (unsigned char*)d_ws;
    float* scores = (float*)(ws + WS_SCORES);

    prep_kernel<<<41, 256, 0, stream>>>(hidden, W_attn, b_attn, ws, out);
    gemm_scores_kernel<<<T_ * B_ / BM, 512, 0, stream>>>(enc, ws, v, scores);
    softmax_kernel<<<B_, 1024, 0, stream>>>(scores, out + B_ * D_);
    context_kernel<<<B_ * 64, 256, 0, stream>>>(enc, out + B_ * D_, out);
}

// Round 3
// 460.228 us; speedup vs baseline: 1.6079x; 1.6079x over previous
//
#include <hip/hip_runtime.h>
#include <math.h>

#define B_  32
#define T_  4096
#define H_  256
#define D_  512

// ws layout (bytes):
//   pre    : float [32*256]    @ 0        (h_proj + b_attn)
//   we_hi  : ushort[256*512]   @ 32768
//   scores : float [32*4096]   @ 557056
#define WS_PRE    0
#define WS_WEHI   32768
#define WS_SCORES 557056

using short8  = __attribute__((ext_vector_type(8))) short;
using float4v = __attribute__((ext_vector_type(4))) float;

__device__ __forceinline__ unsigned short f32_to_bf16_rne(float x) {
    unsigned u = __float_as_uint(x);
    unsigned r = u + 0x7fffu + ((u >> 16) & 1u);
    return (unsigned short)(r >> 16);
}

// ---------------------------------------------------------------- prep ------
__global__ __launch_bounds__(256)
void prep_kernel(const float* __restrict__ hidden,
                 const float* __restrict__ W_attn,
                 const float* __restrict__ b_attn,
                 unsigned char* __restrict__ ws,
                 float* __restrict__ out_ctx) {
    int blk = blockIdx.x;
    int tid = threadIdx.x;
    if (blk < 32) {
        int b = blk, h = tid;
        const float4* hv = (const float4*)(hidden + b * D_);
        const float4* wv = (const float4*)(W_attn + (size_t)h * 1024);
        float s = 0.f;
        #pragma unroll 4
        for (int d4 = 0; d4 < D_ / 4; ++d4) {
            float4 a = hv[d4], w = wv[d4];
            s += a.x * w.x + a.y * w.y + a.z * w.z + a.w * w.w;
        }
        ((float*)(ws + WS_PRE))[b * H_ + h] = s + b_attn[h];
    } else if (blk < 40) {
        int base = (blk - 32) * 16384 + tid;
        unsigned short* whi = (unsigned short*)(ws + WS_WEHI);
        #pragma unroll 4
        for (int i = 0; i < 64; ++i) {
            int idx = base + i * 256;          // 0..131071
            int n = idx >> 9, k = idx & 511;
            whi[idx] = f32_to_bf16_rne(W_attn[(size_t)n * 1024 + 512 + k]);
        }
    } else {
        for (int i = tid; i < B_ * D_; i += 256) out_ctx[i] = 0.f;
    }
}

// --------------------------------------------------- GEMM + tanh + v-dot ----
// grid = 1024 blocks (M-tiles of 128), 512 threads (8 waves, 2m x 4n, 64x64).
// BM=128 x BN=256 (full N) x K=512, BK=32. Plain bf16 (rne) both operands.
// Double-buffered LDS, ONE lgkm-only barrier per k-iter, 2-slab-deep
// register prefetch (loads never drained by a vmcnt(0) barrier).
#define BM 128
#define BN 256
#define BK 32
#define LDT 40   // LDS row stride in ushorts: 80B rows -> 2-way-only bank alias (free)

__global__ __launch_bounds__(512, 4)
void gemm_scores_kernel(const float* __restrict__ enc,
                        const unsigned char* __restrict__ ws_ro,
                        const float* __restrict__ v,
                        float* __restrict__ scores_out) {
    __shared__ unsigned short sA[2][BM * LDT];
    __shared__ unsigned short sB[2][BN * LDT];
    __shared__ float sScore[BM];

    const float*          pre = (const float*)(ws_ro + WS_PRE);
    const unsigned short* weh = (const unsigned short*)(ws_ro + WS_WEHI);

    int tid = threadIdx.x;
    int m0  = blockIdx.x * BM;
    int b   = m0 >> 12;

    if (tid < BM) sScore[tid] = 0.f;

    // A staging: rowA consecutive within a wave -> contiguous LDS writes
    int rowA = tid & 127, cgA = tid >> 7;          // 4 col-groups of 8 floats
    const float* gA = enc + (size_t)(m0 + rowA) * D_ + cgA * 8;
    // B staging: 2 threads per n-row, 16 ushorts each
    int rowB = tid >> 1, hB = tid & 1;
    const unsigned short* gB = weh + (size_t)rowB * D_ + hB * 16;

    int wave = tid >> 6, lane = tid & 63;
    int wm = wave & 1, wn = wave >> 1;             // 2 x 4 waves, 64x64 tiles
    int quad = lane >> 4, l16 = lane & 15;

    float4v acc[4][4] = {};

    float a_reg[8];
    uint4 br0, br1;

    // ---- preamble: slab 0 -> buf0, then start slab 1 loads
    {
        const float4* p = (const float4*)gA;
        *(float4*)(a_reg)     = p[0];
        *(float4*)(a_reg + 4) = p[1];
        br0 = ((const uint4*)gB)[0]; br1 = ((const uint4*)gB)[1];

        unsigned short hi8[8];
        #pragma unroll
        for (int j = 0; j < 8; ++j) hi8[j] = f32_to_bf16_rne(a_reg[j]);
        *(short8*)&sA[0][rowA * LDT + cgA * 8] = *(short8*)hi8;
        *(uint4*)&sB[0][rowB * LDT + hB * 16]     = br0;
        *(uint4*)&sB[0][rowB * LDT + hB * 16 + 8] = br1;

        const float4* p1 = (const float4*)(gA + BK);
        *(float4*)(a_reg)     = p1[0];
        *(float4*)(a_reg + 4) = p1[1];
        const uint4* pb1 = (const uint4*)(gB + BK);
        br0 = pb1[0]; br1 = pb1[1];
    }
    __builtin_amdgcn_s_waitcnt(0xc07f);   // lgkmcnt(0) only — vmcnt left alone
    __builtin_amdgcn_s_barrier();

    const int KIT = D_ / BK;   // 16
    for (int kk = 0; kk < KIT; ++kk) {
        int cur = kk & 1, nxt = cur ^ 1;

        // fragment reads for this slab
        short8 ah[4], bh[4];
        #pragma unroll
        for (int i = 0; i < 4; ++i) {
            int r = wm * 64 + i * 16 + l16;
            ah[i] = *(const short8*)&sA[cur][r * LDT + quad * 8];
        }
        #pragma unroll
        for (int j = 0; j < 4; ++j) {
            int c = wn * 64 + j * 16 + l16;
            bh[j] = *(const short8*)&sB[cur][c * LDT + quad * 8];
        }

        // convert + stage slab kk+1 into the other buffer
        if (kk + 1 < KIT) {
            unsigned short hi8[8];
            #pragma unroll
            for (int j = 0; j < 8; ++j) hi8[j] = f32_to_bf16_rne(a_reg[j]);
            *(short8*)&sA[nxt][rowA * LDT + cgA * 8] = *(short8*)hi8;
            *(uint4*)&sB[nxt][rowB * LDT + hB * 16]     = br0;
            *(uint4*)&sB[nxt][rowB * LDT + hB * 16 + 8] = br1;
        }
        // issue global loads for slab kk+2 (in flight through next iteration)
        if (kk + 2 < KIT) {
            const float4* p = (const float4*)(gA + (kk + 2) * BK);
            *(float4*)(a_reg)     = p[0];
            *(float4*)(a_reg + 4) = p[1];
            const uint4* pb = (const uint4*)(gB + (kk + 2) * BK);
            br0 = pb[0]; br1 = pb[1];
        }

        #pragma unroll
        for (int i = 0; i < 4; ++i)
            #pragma unroll
            for (int j = 0; j < 4; ++j)
                acc[i][j] = __builtin_amdgcn_mfma_f32_16x16x32_bf16(ah[i], bh[j], acc[i][j], 0, 0, 0);

        if (kk + 1 < KIT) {
            __builtin_amdgcn_s_waitcnt(0xc07f);   // drain LDS writes only
            __builtin_amdgcn_s_barrier();
        }
    }

    // epilogue: energy = tanh(acc + pre[b][n]); score_row += energy * v[n]
    float rowsum[4][4] = {};
    #pragma unroll
    for (int j = 0; j < 4; ++j) {
        int n = wn * 64 + j * 16 + l16;
        float pv = pre[b * H_ + n];
        float vv = v[n];
        #pragma unroll
        for (int i = 0; i < 4; ++i)
            #pragma unroll
            for (int r = 0; r < 4; ++r)
                rowsum[i][r] += tanhf(acc[i][j][r] + pv) * vv;
    }
    #pragma unroll
    for (int i = 0; i < 4; ++i)
        #pragma unroll
        for (int r = 0; r < 4; ++r) {
            float s = rowsum[i][r];
            s += __shfl_xor(s, 1);
            s += __shfl_xor(s, 2);
            s += __shfl_xor(s, 4);
            s += __shfl_xor(s, 8);
            rowsum[i][r] = s;
        }
    if (l16 == 0) {
        #pragma unroll
        for (int i = 0; i < 4; ++i)
            #pragma unroll
            for (int r = 0; r < 4; ++r) {
                int row = wm * 64 + i * 16 + quad * 4 + r;
                atomicAdd(&sScore[row], rowsum[i][r]);
            }
    }
    __syncthreads();
    if (tid < BM) scores_out[m0 + tid] = sScore[tid];
}

// ------------------------------------------------------------- softmax ------
__global__ __launch_bounds__(1024)
void softmax_kernel(const float* __restrict__ scores, float* __restrict__ wout) {
    __shared__ float red[16];
    int b = blockIdx.x, tid = threadIdx.x;
    int wave = tid >> 6, lane = tid & 63;
    float4 x = ((const float4*)(scores + (size_t)b * T_))[tid];

    float m = fmaxf(fmaxf(x.x, x.y), fmaxf(x.z, x.w));
    #pragma unroll
    for (int off = 32; off; off >>= 1) m = fmaxf(m, __shfl_xor(m, off));
    if (lane == 0) red[wave] = m;
    __syncthreads();
    if (wave == 0) {
        float t = (lane < 16) ? red[lane] : -1e30f;
        #pragma unroll
        for (int off = 8; off; off >>= 1) t = fmaxf(t, __shfl_xor(t, off));
        if (lane == 0) red[0] = t;
    }
    __syncthreads();
    m = red[0];
    __syncthreads();

    float4 e;
    e.x = expf(x.x - m); e.y = expf(x.y - m);
    e.z = expf(x.z - m); e.w = expf(x.w - m);
    float s = e.x + e.y + e.z + e.w;
    #pragma unroll
    for (int off = 32; off; off >>= 1) s += __shfl_xor(s, off);
    if (lane == 0) red[wave] = s;
    __syncthreads();
    if (wave == 0) {
        float t = (lane < 16) ? red[lane] : 0.f;
        #pragma unroll
        for (int off = 8; off; off >>= 1) t += __shfl_xor(t, off);
        if (lane == 0) red[0] = t;
    }
    __syncthreads();
    float inv = 1.0f / red[0];

    float4 o;
    o.x = e.x * inv; o.y = e.y * inv; o.z = e.z * inv; o.w = e.w * inv;
    ((float4*)(wout + (size_t)b * T_))[tid] = o;
}

// ------------------------------------------------------------- context ------
__global__ __launch_bounds__(256)
void context_kernel(const float* __restrict__ enc,
                    const float* __restrict__ w,
                    float* __restrict__ ctx) {
    int blk = blockIdx.x;
    int b = blk >> 6, chunk = blk & 63;
    int tid = threadIdx.x;
    int colg = tid & 127, rh = tid >> 7;
    const float* encb = enc + (size_t)b * T_ * D_;
    int t0 = chunk * 64;

    float4 acc = {0.f, 0.f, 0.f, 0.f};
    #pragma unroll 8
    for (int s = 0; s < 32; ++s) {
        int t = t0 + rh + 2 * s;
        float wt = w[(size_t)b * T_ + t];
        float4 ev = *(const float4*)(encb + (size_t)t * D_ + colg * 4);
        acc.x += wt * ev.x; acc.y += wt * ev.y;
        acc.z += wt * ev.z; acc.w += wt * ev.w;
    }
    __shared__ float4 sred[128];
    if (rh == 1) sred[colg] = acc;
    __syncthreads();
    if (rh == 0) {
        float4 o = sred[colg];
        acc.x += o.x; acc.y += o.y; acc.z += o.z; acc.w += o.w;
        float* dst = ctx + (size_t)b * D_ + colg * 4;
        atomicAdd(dst + 0, acc.x);
        atomicAdd(dst + 1, acc.y);
        atomicAdd(dst + 2, acc.z);
        atomicAdd(dst + 3, acc.w);
    }
}

// ------------------------------------------------------------- launcher -----
extern "C" void kernel_launch(void* const* d_in, const int* in_sizes, int n_in,
                              void* d_out, int out_size, void* d_ws, size_t ws_size,
                              hipStream_t stream) {
    const float* hidden = (const float*)d_in[0];   // (32, 512)
    const float* enc    = (const float*)d_in[1];   // (32, 4096, 512)
    const float* W_attn = (const float*)d_in[2];   // (256, 1024)
    const float* b_attn = (const float*)d_in[3];   // (256,)
    const float* v      = (const float*)d_in[4];   // (256,)
    float* out = (float*)d_out;                    // context(16384) ++ weights(131072)
    unsigned char* ws = (unsigned char*)d_ws;
    float* scores = (float*)(ws + WS_SCORES);

    prep_kernel<<<41, 256, 0, stream>>>(hidden, W_attn, b_attn, ws, out);
    gemm_scores_kernel<<<T_ * B_ / BM, 512, 0, stream>>>(enc, ws, v, scores);
    softmax_kernel<<<B_, 1024, 0, stream>>>(scores, out + B_ * D_);
    context_kernel<<<B_ * 64, 256, 0, stream>>>(enc, out + B_ * D_, out);
}

// Round 4
// 439.274 us; speedup vs baseline: 1.6846x; 1.0477x over previous
//
#include <hip/hip_runtime.h>
#include <math.h>

#define B_  32
#define T_  4096
#define H_  256
#define D_  512

// ws layout (bytes):
//   pre   : float [32*256]        @ 0       (h_proj + b_attn)
//   we_hi : ushort[256*512]       @ 32768
//   p     : float [32*4096]       @ 294912  (exp(s - m_blk) per row)
//   ml    : float2[1024]          @ 819200  (per-tile m_blk, l_blk)
//   pctx  : float [1024*512]      @ 827392  (per-tile partial context)
#define WS_PRE    0
#define WS_WEHI   32768
#define WS_P      294912
#define WS_ML     819200
#define WS_PCTX   827392

using short8  = __attribute__((ext_vector_type(8))) short;
using float4v = __attribute__((ext_vector_type(4))) float;

__device__ __forceinline__ unsigned short f32_to_bf16_rne(float x) {
    unsigned u = __float_as_uint(x);
    unsigned r = u + 0x7fffu + ((u >> 16) & 1u);
    return (unsigned short)(r >> 16);
}

// ---------------------------------------------------------------- prep ------
__global__ __launch_bounds__(256)
void prep_kernel(const float* __restrict__ hidden,
                 const float* __restrict__ W_attn,
                 const float* __restrict__ b_attn,
                 unsigned char* __restrict__ ws) {
    int blk = blockIdx.x;
    int tid = threadIdx.x;
    if (blk < 32) {
        int b = blk, h = tid;
        const float4* hv = (const float4*)(hidden + b * D_);
        const float4* wv = (const float4*)(W_attn + (size_t)h * 1024);
        float s = 0.f;
        #pragma unroll 4
        for (int d4 = 0; d4 < D_ / 4; ++d4) {
            float4 a = hv[d4], w = wv[d4];
            s += a.x * w.x + a.y * w.y + a.z * w.z + a.w * w.w;
        }
        ((float*)(ws + WS_PRE))[b * H_ + h] = s + b_attn[h];
    } else {
        int base = (blk - 32) * 16384 + tid;
        unsigned short* whi = (unsigned short*)(ws + WS_WEHI);
        #pragma unroll 4
        for (int i = 0; i < 64; ++i) {
            int idx = base + i * 256;          // 0..131071
            int n = idx >> 9, k = idx & 511;
            whi[idx] = f32_to_bf16_rne(W_attn[(size_t)n * 1024 + 512 + k]);
        }
    }
}

// ------------------------------- GEMM + tanh + v-dot + local softmax + pctx -
// grid = 1024 blocks (M-tiles of 128), 512 threads (8 waves, 2m x 4n, 64x64).
// BM=128 x BN=256 (full N) x K=512, BK=32. Plain bf16 (rne) both operands.
// Double-buffered LDS, one lgkm-only barrier per k-iter, 2-slab prefetch.
// Epilogue: scores -> local softmax (m,l,p) -> partial context from the
// block's own enc slab (L2/L3-hot re-read, no second HBM pass).
#define BM 128
#define BN 256
#define BK 32
#define LDT 40   // LDS row stride in ushorts: 80B rows -> 2-way-only bank alias

__global__ __launch_bounds__(512, 4)
void gemm_scores_kernel(const float* __restrict__ enc,
                        unsigned char* __restrict__ ws,
                        const float* __restrict__ v) {
    __shared__ unsigned short sA[2][BM * LDT];
    __shared__ unsigned short sB[2][BN * LDT];
    __shared__ float sScore[BM];
    __shared__ float sP[BM];
    __shared__ float sRed[4];

    const float*          pre = (const float*)(ws + WS_PRE);
    const unsigned short* weh = (const unsigned short*)(ws + WS_WEHI);

    int tid = threadIdx.x;
    int m0  = blockIdx.x * BM;
    int b   = m0 >> 12;

    if (tid < BM) sScore[tid] = 0.f;

    // A staging: rowA consecutive within a wave -> contiguous LDS writes
    int rowA = tid & 127, cgA = tid >> 7;          // 4 col-groups of 8 floats
    const float* gA = enc + (size_t)(m0 + rowA) * D_ + cgA * 8;
    // B staging: 2 threads per n-row, 16 ushorts each
    int rowB = tid >> 1, hB = tid & 1;
    const unsigned short* gB = weh + (size_t)rowB * D_ + hB * 16;

    int wave = tid >> 6, lane = tid & 63;
    int wm = wave & 1, wn = wave >> 1;             // 2 x 4 waves, 64x64 tiles
    int quad = lane >> 4, l16 = lane & 15;

    float4v acc[4][4] = {};

    float a_reg[8];
    uint4 br0, br1;

    // ---- preamble: slab 0 -> buf0, then start slab 1 loads
    {
        const float4* p = (const float4*)gA;
        *(float4*)(a_reg)     = p[0];
        *(float4*)(a_reg + 4) = p[1];
        br0 = ((const uint4*)gB)[0]; br1 = ((const uint4*)gB)[1];

        unsigned short hi8[8];
        #pragma unroll
        for (int j = 0; j < 8; ++j) hi8[j] = f32_to_bf16_rne(a_reg[j]);
        *(short8*)&sA[0][rowA * LDT + cgA * 8] = *(short8*)hi8;
        *(uint4*)&sB[0][rowB * LDT + hB * 16]     = br0;
        *(uint4*)&sB[0][rowB * LDT + hB * 16 + 8] = br1;

        const float4* p1 = (const float4*)(gA + BK);
        *(float4*)(a_reg)     = p1[0];
        *(float4*)(a_reg + 4) = p1[1];
        const uint4* pb1 = (const uint4*)(gB + BK);
        br0 = pb1[0]; br1 = pb1[1];
    }
    __builtin_amdgcn_s_waitcnt(0xc07f);   // lgkmcnt(0) only
    __builtin_amdgcn_s_barrier();

    const int KIT = D_ / BK;   // 16
    for (int kk = 0; kk < KIT; ++kk) {
        int cur = kk & 1, nxt = cur ^ 1;

        short8 ah[4], bh[4];
        #pragma unroll
        for (int i = 0; i < 4; ++i) {
            int r = wm * 64 + i * 16 + l16;
            ah[i] = *(const short8*)&sA[cur][r * LDT + quad * 8];
        }
        #pragma unroll
        for (int j = 0; j < 4; ++j) {
            int c = wn * 64 + j * 16 + l16;
            bh[j] = *(const short8*)&sB[cur][c * LDT + quad * 8];
        }

        if (kk + 1 < KIT) {
            unsigned short hi8[8];
            #pragma unroll
            for (int j = 0; j < 8; ++j) hi8[j] = f32_to_bf16_rne(a_reg[j]);
            *(short8*)&sA[nxt][rowA * LDT + cgA * 8] = *(short8*)hi8;
            *(uint4*)&sB[nxt][rowB * LDT + hB * 16]     = br0;
            *(uint4*)&sB[nxt][rowB * LDT + hB * 16 + 8] = br1;
        }
        if (kk + 2 < KIT) {
            const float4* p = (const float4*)(gA + (kk + 2) * BK);
            *(float4*)(a_reg)     = p[0];
            *(float4*)(a_reg + 4) = p[1];
            const uint4* pb = (const uint4*)(gB + (kk + 2) * BK);
            br0 = pb[0]; br1 = pb[1];
        }

        #pragma unroll
        for (int i = 0; i < 4; ++i)
            #pragma unroll
            for (int j = 0; j < 4; ++j)
                acc[i][j] = __builtin_amdgcn_mfma_f32_16x16x32_bf16(ah[i], bh[j], acc[i][j], 0, 0, 0);

        if (kk + 1 < KIT) {
            __builtin_amdgcn_s_waitcnt(0xc07f);
            __builtin_amdgcn_s_barrier();
        }
    }

    // ---- scores: energy = tanh(acc + pre[b][n]); rowsum += energy * v[n]
    float rowsum[4][4] = {};
    #pragma unroll
    for (int j = 0; j < 4; ++j) {
        int n = wn * 64 + j * 16 + l16;
        float pv = pre[b * H_ + n];
        float vv = v[n];
        #pragma unroll
        for (int i = 0; i < 4; ++i)
            #pragma unroll
            for (int r = 0; r < 4; ++r)
                rowsum[i][r] += tanhf(acc[i][j][r] + pv) * vv;
    }
    #pragma unroll
    for (int i = 0; i < 4; ++i)
        #pragma unroll
        for (int r = 0; r < 4; ++r) {
            float s = rowsum[i][r];
            s += __shfl_xor(s, 1);
            s += __shfl_xor(s, 2);
            s += __shfl_xor(s, 4);
            s += __shfl_xor(s, 8);
            rowsum[i][r] = s;
        }
    if (l16 == 0) {
        #pragma unroll
        for (int i = 0; i < 4; ++i)
            #pragma unroll
            for (int r = 0; r < 4; ++r) {
                int row = wm * 64 + i * 16 + quad * 4 + r;
                atomicAdd(&sScore[row], rowsum[i][r]);
            }
    }
    __syncthreads();

    // ---- local softmax over the 128 rows
    if (tid < 128) {
        float s = sScore[tid];
        float m = s;
        #pragma unroll
        for (int off = 32; off; off >>= 1) m = fmaxf(m, __shfl_xor(m, off));
        if (lane == 0) sRed[wave] = m;
    }
    __syncthreads();
    float m_blk = fmaxf(sRed[0], sRed[1]);
    if (tid < 128) {
        float p = expf(sScore[tid] - m_blk);
        sP[tid] = p;
        ((float*)(ws + WS_P))[m0 + tid] = p;
        float l = p;
        #pragma unroll
        for (int off = 32; off; off >>= 1) l += __shfl_xor(l, off);
        if (lane == 0) sRed[2 + wave] = l;
    }
    __syncthreads();
    if (tid == 0) {
        float2 ml = make_float2(m_blk, sRed[2] + sRed[3]);
        ((float2*)(ws + WS_ML))[blockIdx.x] = ml;
    }

    // ---- partial context: re-read own slab (cache-hot), weight by p
    int colg = tid & 127, rgrp = tid >> 7;     // 128 d-groups x 4 rows in flight
    const float* encb = enc + (size_t)m0 * D_;
    float4 c4 = {0.f, 0.f, 0.f, 0.f};
    #pragma unroll 4
    for (int s = 0; s < 32; ++s) {
        int r = rgrp + 4 * s;
        float w = sP[r];
        float4 ev = *(const float4*)(encb + (size_t)r * D_ + colg * 4);
        c4.x += w * ev.x; c4.y += w * ev.y;
        c4.z += w * ev.z; c4.w += w * ev.w;
    }
    float4* red4 = (float4*)sA;                 // reuse LDS (frags long dead)
    red4[tid] = c4;
    __syncthreads();
    if (rgrp == 0) {
        float4 a0 = red4[colg], a1 = red4[colg + 128];
        float4 a2 = red4[colg + 256], a3 = red4[colg + 384];
        float4 o;
        o.x = a0.x + a1.x + a2.x + a3.x;
        o.y = a0.y + a1.y + a2.y + a3.y;
        o.z = a0.z + a1.z + a2.z + a3.z;
        o.w = a0.w + a1.w + a2.w + a3.w;
        ((float4*)(ws + WS_PCTX))[blockIdx.x * 128 + colg] = o;
    }
}

// ------------------------------------------------------------ finalize ------
// one block per batch: combine 32 tile partials, write weights + context.
__global__ __launch_bounds__(512)
void finalize_kernel(const unsigned char* __restrict__ ws,
                     float* __restrict__ out_ctx,
                     float* __restrict__ out_w) {
    __shared__ float sm[32], sl[32], sscale[32];
    int b = blockIdx.x, tid = threadIdx.x;
    const float2* ml  = ((const float2*)(ws + WS_ML)) + b * 32;
    if (tid < 32) {
        float2 v = ml[tid];
        sm[tid] = v.x; sl[tid] = v.y;
    }
    __syncthreads();
    float m = -1e30f;
    #pragma unroll
    for (int i = 0; i < 32; ++i) m = fmaxf(m, sm[i]);
    float l = 0.f;
    #pragma unroll
    for (int i = 0; i < 32; ++i) l += sl[i] * expf(sm[i] - m);
    float inv = 1.0f / l;
    if (tid < 32) sscale[tid] = expf(sm[tid] - m) * inv;
    __syncthreads();

    // weights: 4096 per batch, 8 per thread (same tile per group of 8)
    {
        const float4* pb = (const float4*)((const float*)(ws + WS_P) + (size_t)b * T_);
        float4* wb = (float4*)(out_w + (size_t)b * T_);
        int t0 = tid * 2;                 // float4 index; tile = (tid*8)>>7
        float sc = sscale[tid >> 4];
        float4 x = pb[t0], y = pb[t0 + 1];
        x.x *= sc; x.y *= sc; x.z *= sc; x.w *= sc;
        y.x *= sc; y.y *= sc; y.z *= sc; y.w *= sc;
        wb[t0] = x; wb[t0 + 1] = y;
    }
    // context: 512 d per batch, 1 per thread
    {
        const float* pc = (const float*)(ws + WS_PCTX) + (size_t)b * 32 * D_;
        float c = 0.f;
        #pragma unroll
        for (int i = 0; i < 32; ++i) c += pc[i * D_ + tid] * sscale[i];
        out_ctx[b * D_ + tid] = c;
    }
}

// ------------------------------------------------------------- launcher -----
extern "C" void kernel_launch(void* const* d_in, const int* in_sizes, int n_in,
                              void* d_out, int out_size, void* d_ws, size_t ws_size,
                              hipStream_t stream) {
    const float* hidden = (const float*)d_in[0];   // (32, 512)
    const float* enc    = (const float*)d_in[1];   // (32, 4096, 512)
    const float* W_attn = (const float*)d_in[2];   // (256, 1024)
    const float* b_attn = (const float*)d_in[3];   // (256,)
    const float* v      = (const float*)d_in[4];   // (256,)
    float* out = (float*)d_out;                    // context(16384) ++ weights(131072)
    unsigned char* ws = (unsigned char*)d_ws;

    prep_kernel<<<40, 256, 0, stream>>>(hidden, W_attn, b_attn, ws);
    gemm_scores_kernel<<<T_ * B_ / BM, 512, 0, stream>>>(enc, ws, v);
    finalize_kernel<<<B_, 512, 0, stream>>>(ws, out, out + B_ * D_);
}